// Round 11
// baseline (145.999 us; speedup 1.0000x reference)
//
#include <hip/hip_runtime.h>

// Locally-connected 2x2 conv, unshared weights.
// x: [256 planes, 512, 512] f32; weights: [511*511, 4]; bias: [511*511]
// out: [256, 511, 511]; out row 0 / col 0 are zero.
// neuron index = 511*w + h == flat in-plane output index.
//
// v11: fix the silent register starvation. v7-v10 used launch_bounds(256,8)
// and the compiler allocated 24-32 VGPR -- too few to hold the per-thread
// weight tile across the plane loop, so it RE-LOADED weights+bias from cache
// every iteration (the "weights in registers" design never existed).
// Now: thread = 8 flat outputs, launch_bounds(256,4) -> 128 VGPR budget,
// weights (8x float4), bias (8) and x row temps genuinely live in registers.
// 1024 blocks (4/CU, 16 waves/CU), XCD-mapped grid(8,128), plane grid-stride.
// All streams dense dwordx4-class; borders = computed zeros in-stream.

typedef float f4u __attribute__((ext_vector_type(4), aligned(4)));
typedef float f2u __attribute__((ext_vector_type(2), aligned(4)));

constexpr int PLANE_OUT = 511 * 511;    // 261121
constexpr int PLANE_IN  = 512 * 512;    // 262144
constexpr int PSTRIDE   = 8;            // plane phases == XCD count

__global__ __launch_bounds__(256, 4)    // 128 VGPR budget; 16 waves/CU
void lc_conv2x2_v11(const float* __restrict__ x,
                    const float4* __restrict__ weights,
                    const float* __restrict__ bias,
                    float* __restrict__ out, int planes) {
    const int q  = blockIdx.x;                  // 0..7 plane phase == XCD
    const int jb = blockIdx.y;                  // 0..127
    const int t  = threadIdx.x;
    const int o0 = (jb << 11) + (t << 3);       // 8 outputs per thread
    if (o0 >= PLANE_OUT) return;                // block 127 high threads

    const int w  = o0 / 511;
    const int h  = o0 - w * 511;
    const int tb = o0 + w - 513;                // x idx of top-left tap
    const int bb = tb + 512;

    // slow path: x base underflow (w==0 region) or output-count tail
    if (tb < 0 || o0 + 8 > PLANE_OUT) {
        int    gx[8]; bool vz[8]; float4 wtj[8]; float bvj[8];
        #pragma unroll
        for (int j = 0; j < 8; ++j) {
            const int o  = o0 + j;
            const bool valid = (o < PLANE_OUT);
            const int oc = valid ? o : (PLANE_OUT - 1);
            const int wj = oc / 511, hj = oc - wj * 511;
            const bool z = (wj == 0) || (hj == 0);
            vz[j] = valid && !z;
            gx[j] = z ? 0 : (512 * (wj - 1) + hj - 1);
            if (valid) { wtj[j] = weights[oc]; bvj[j] = bias[oc]; }
        }
        for (int p = q; p < planes; p += PSTRIDE) {
            const float* xp = x   + (size_t)p * PLANE_IN;
            float*       op = out + (size_t)p * PLANE_OUT;
            #pragma unroll
            for (int j = 0; j < 8; ++j) {
                if (o0 + j >= PLANE_OUT) continue;
                float v = 0.0f;
                if (vz[j])
                    v = xp[gx[j]]       * wtj[j].x + xp[gx[j] + 1]   * wtj[j].y
                      + xp[gx[j] + 512] * wtj[j].z + xp[gx[j] + 513] * wtj[j].w
                      + bvj[j];
                op[o0 + j] = v;
            }
        }
        return;
    }

    // ---- fast path: w >= 1 guaranteed (tb >= 0). Plane-invariant predicates.
    bool cj[8], zj[8];
    #pragma unroll
    for (int j = 0; j < 8; ++j) {
        const int hr = h + j;
        cj[j] = (hr >= 511);                    // crosses into row w+1
        const int hj = hr - (cj[j] ? 511 : 0);
        zj[j] = (hj == 0);                      // col-0 border (row-0 impossible)
    }

    // weights + bias -> registers, once per block (now they actually fit)
    float4 wtr[8];
    #pragma unroll
    for (int j = 0; j < 8; ++j) wtr[j] = weights[o0 + j];
    const f4u bv0 = *(const f4u*)(bias + o0);
    const f4u bv1 = *(const f4u*)(bias + o0 + 4);
    const float bvr[8] = {bv0.x, bv0.y, bv0.z, bv0.w, bv1.x, bv1.y, bv1.z, bv1.w};

    #pragma unroll 2
    for (int p = q; p < planes; p += PSTRIDE) {
        const float* xp = x + (size_t)p * PLANE_IN;

        f4u T0 = *(const f4u*)(xp + tb);        // top row: 10 floats
        f4u T1 = *(const f4u*)(xp + tb + 4);
        f2u T2 = *(const f2u*)(xp + tb + 8);
        f4u B0 = *(const f4u*)(xp + bb);        // bottom row: 10 floats
        f4u B1 = *(const f4u*)(xp + bb + 4);
        f2u B2 = *(const f2u*)(xp + bb + 8);
        const float tv[10] = {T0.x, T0.y, T0.z, T0.w, T1.x, T1.y, T1.z, T1.w, T2.x, T2.y};
        const float bw[10] = {B0.x, B0.y, B0.z, B0.w, B1.x, B1.y, B1.z, B1.w, B2.x, B2.y};

        f4u r0, r1;
        #pragma unroll
        for (int j = 0; j < 8; ++j) {           // static indices; cj -> cndmask
            const float xtl = cj[j] ? tv[j + 1] : tv[j];
            const float xtr = cj[j] ? tv[j + 2] : tv[j + 1];
            const float xbl = cj[j] ? bw[j + 1] : bw[j];
            const float xbr = cj[j] ? bw[j + 2] : bw[j + 1];
            const float v = xtl * wtr[j].x + xtr * wtr[j].y
                          + xbl * wtr[j].z + xbr * wtr[j].w + bvr[j];
            if (j < 4) r0[j] = zj[j] ? 0.0f : v;
            else       r1[j - 4] = zj[j] ? 0.0f : v;
        }
        float* op = out + (size_t)p * PLANE_OUT + o0;
        *(f4u*)(op)     = r0;                   // two dense dwordx4 stores
        *(f4u*)(op + 4) = r1;
    }
}

extern "C" void kernel_launch(void* const* d_in, const int* in_sizes, int n_in,
                              void* d_out, int out_size, void* d_ws, size_t ws_size,
                              hipStream_t stream) {
    const float*  x       = (const float*)d_in[0];
    const float4* weights = (const float4*)d_in[1];
    const float*  bias    = (const float*)d_in[2];
    float*        out     = (float*)d_out;

    int planes = in_sizes[0] / PLANE_IN;        // 256
    dim3 grid(PSTRIDE, 128);                    // 1024 blocks, 4/CU, XCD = q
    lc_conv2x2_v11<<<grid, 256, 0, stream>>>(x, weights, bias, out, planes);
}

// Round 12
// 113.211 us; speedup vs baseline: 1.2896x; 1.2896x over previous
//
#include <hip/hip_runtime.h>

// Locally-connected 2x2 conv, unshared weights.
// x: [256 planes, 512, 512] f32; weights: [511*511, 4]; bias: [511*511]
// out: [256, 511, 511]; out row 0 / col 0 are zero.
// neuron index = 511*w + h == flat in-plane output index.
//
// v12 = v10 (best: 136.8us) + NONTEMPORAL full-line stores.
// Mechanism: out (267MB) streaming through L2/L3 evicts x (268MB) from the
// 256MB L3 between timed replays; FETCH=165MB shows x only ~60% retained.
// nt stores keep out from consuming L3 capacity -> x retention rises ->
// FETCH drops. Unlike v4's nt disaster (scalar stride-16B partial lines),
// these stores are full 64B lines (4 lanes x dwordx4), so no amplification.
// Everything else byte-identical to v10.

typedef float f4u __attribute__((ext_vector_type(4), aligned(4)));
typedef float f2u __attribute__((ext_vector_type(2), aligned(4)));

constexpr int PLANE_OUT = 511 * 511;    // 261121
constexpr int PLANE_IN  = 512 * 512;    // 262144
constexpr int PSTRIDE   = 8;            // plane phases == XCD count

__global__ __launch_bounds__(256, 8)    // <=64 VGPR: all 2048 blocks resident
void lc_conv2x2_v12(const float* __restrict__ x,
                    const float4* __restrict__ weights,
                    const float* __restrict__ bias,
                    float* __restrict__ out, int planes) {
    const int q = blockIdx.x;           // 0..7 plane phase == XCD
    const int b = blockIdx.y;           // 0..255
    const int t = threadIdx.x;

    if (b == 255) {                     // tail block: single output o = 261120
        if (t != 0) return;             // (w,h) = (510,510)
        const float4 wt = weights[PLANE_OUT - 1];
        const float  bv = bias[PLANE_OUT - 1];
        for (int p = q; p < planes; p += PSTRIDE) {
            const float* xp = x + (size_t)p * PLANE_IN;
            float v = xp[509 * 512 + 509] * wt.x + xp[509 * 512 + 510] * wt.y
                    + xp[510 * 512 + 509] * wt.z + xp[510 * 512 + 510] * wt.w + bv;
            out[(size_t)p * PLANE_OUT + (PLANE_OUT - 1)] = v;
        }
        return;
    }

    const int o0 = (b << 10) | (t << 2);        // 0..261116, multiple of 4
    const int w  = o0 / 511;                    // hoisted magic-div
    const int h  = o0 - w * 511;

    // plane-invariant per-j predicates: crossing + force-zero (borders)
    bool cj[4], zj[4];
    #pragma unroll
    for (int j = 0; j < 4; ++j) {
        const int hr = h + j;
        cj[j] = (hr >= 511);                    // crosses into row w+1
        const int wj = w + (cj[j] ? 1 : 0);
        const int hj = hr - (cj[j] ? 511 : 0);
        zj[j] = (wj == 0) || (hj == 0);         // row-0 / col-0 border
    }

    // weights/bias -> registers, once per block
    float4 wtr[4];
    #pragma unroll
    for (int j = 0; j < 4; ++j) wtr[j] = weights[o0 + j];
    const f4u bv4 = *(const f4u*)(bias + o0);

    // x bases: top-left of output o0 = flat(w-1, h-1) = o0 + w - 513
    int tb = o0 + w - 513;
    if (tb < 0) tb = 0;                         // w==0 rows are forced zero anyway
    const int bb = tb + 512;

    #pragma unroll 2
    for (int p = q; p < planes; p += PSTRIDE) {
        const float* xp = x + (size_t)p * PLANE_IN;

        f4u T0 = *(const f4u*)(xp + tb);        // top row: 6 floats
        f2u T1 = *(const f2u*)(xp + tb + 4);
        f4u B0 = *(const f4u*)(xp + bb);        // bottom row: 6 floats
        f2u B1 = *(const f2u*)(xp + bb + 4);
        const float tv[6] = {T0.x, T0.y, T0.z, T0.w, T1.x, T1.y};
        const float bv[6] = {B0.x, B0.y, B0.z, B0.w, B1.x, B1.y};

        f4u r;
        #pragma unroll
        for (int j = 0; j < 4; ++j) {           // static indices; cj -> cndmask
            const float xtl = cj[j] ? tv[j + 1] : tv[j];
            const float xtr = cj[j] ? tv[j + 2] : tv[j + 1];
            const float xbl = cj[j] ? bv[j + 1] : bv[j];
            const float xbr = cj[j] ? bv[j + 2] : bv[j + 1];
            const float v = xtl * wtr[j].x + xtr * wtr[j].y
                          + xbl * wtr[j].z + xbr * wtr[j].w + bv4[j];
            r[j] = zj[j] ? 0.0f : v;
        }
        // full-line nontemporal store: keep out from evicting x in L2/L3
        __builtin_nontemporal_store(r, (f4u*)(out + (size_t)p * PLANE_OUT + o0));
    }
}

extern "C" void kernel_launch(void* const* d_in, const int* in_sizes, int n_in,
                              void* d_out, int out_size, void* d_ws, size_t ws_size,
                              hipStream_t stream) {
    const float*  x       = (const float*)d_in[0];
    const float4* weights = (const float4*)d_in[1];
    const float*  bias    = (const float*)d_in[2];
    float*        out     = (float*)d_out;

    int planes = in_sizes[0] / PLANE_IN;        // 256
    dim3 grid(PSTRIDE, 256);                    // XCD = blockIdx.x under %8
    lc_conv2x2_v12<<<grid, 256, 0, stream>>>(x, weights, bias, out, planes);
}